// Round 3
// baseline (404.469 us; speedup 1.0000x reference)
//
#include <hip/hip_runtime.h>
#include <hip/hip_bf16.h>
#include <hip/hip_cooperative_groups.h>

namespace cg = cooperative_groups;

// RelationCos pipeline fused into ONE cooperative kernel:
//   phase0: blocks 0-15 run FPS (1 batch each) || blocks 16-255 convert W -> bf16
//   phase1: KNN, 1 wave per (query,set) task (1024 tasks)
//   phase2: gather neighbors -> bf16 A matrices (s and t)
//   phase3: two MFMA GEMMs + BN/ReLU/max epilogue (2 tasks per block)
// grid.sync() between phases; device-scope fences for cross-XCD visibility.

#define NPTS 8192
#define SPTS 32
#define KNN_K 12
#define DS 256
#define DT 1024
#define DOUT 1024
#define NBLK 256
#define NTHR 512

typedef float f32x4 __attribute__((ext_vector_type(4)));
typedef __bf16 bf16x8 __attribute__((ext_vector_type(8)));
typedef unsigned short ushort_t;

struct Params {
    const float* feature_s; const float* xyz_s;
    const float* feature_t; const float* xyz_t;
    const float* Ws; const float* bias_s; const float* gamma_s; const float* beta_s;
    const float* mean_s; const float* var_s;
    const float* Wt; const float* bias_t; const float* gamma_t; const float* beta_t;
    const float* mean_t; const float* var_t;
    float* out;
    float* new_xyz; int* idx_s; int* idx_t;
    ushort_t* Wb_s; ushort_t* Wb_t; ushort_t* A_s; ushort_t* A_t;
};

__device__ __forceinline__ ushort_t f2bf(float f) {
    unsigned int u = __float_as_uint(f);
    u += 0x7fffu + ((u >> 16) & 1u);   // RNE
    return (ushort_t)(u >> 16);
}

// ---------------- FPS (one block per batch, 512 thr, 16 pts/lane) ----------------
__device__ void fps_phase(const float* __restrict__ xyz, float* __restrict__ new_xyz,
                          int b, float rv[2][8], float rx[2][8], float ry[2][8],
                          float rz[2][8], int ri[2][8]) {
#pragma clang fp contract(off)
    int tid = threadIdx.x;
    const float* base = xyz + (size_t)b * NPTS * 3;

    float px[16], py[16], pz[16], dd[16];
#pragma unroll
    for (int i = 0; i < 16; ++i) {
        int p = tid + i * 512;
        px[i] = base[p * 3 + 0];
        py[i] = base[p * 3 + 1];
        pz[i] = base[p * 3 + 2];
        dd[i] = 1e10f;
    }

    float lx = base[0], ly = base[1], lz = base[2];
    if (tid == 0) {
        new_xyz[((size_t)b * SPTS + 0) * 3 + 0] = lx;
        new_xyz[((size_t)b * SPTS + 0) * 3 + 1] = ly;
        new_xyz[((size_t)b * SPTS + 0) * 3 + 2] = lz;
    }

    int w = tid >> 6, lane = tid & 63;
    for (int it = 1; it < SPTS; ++it) {
        int par = it & 1;
        float bv = -1.0f, bx = 0.f, by = 0.f, bz = 0.f;
        int bi = NPTS;
#pragma unroll
        for (int i = 0; i < 16; ++i) {
            float dx = px[i] - lx, dy = py[i] - ly, dz = pz[i] - lz;
            float d = dx * dx + dy * dy;
            d = d + dz * dz;
            float nd = fminf(dd[i], d);
            dd[i] = nd;
            bool t = nd > bv;  // strict >: first occurrence (in-lane ascending index)
            bv = t ? nd : bv;
            bi = t ? (tid + i * 512) : bi;
            bx = t ? px[i] : bx;
            by = t ? py[i] : by;
            bz = t ? pz[i] : bz;
        }
#pragma unroll
        for (int off = 1; off < 64; off <<= 1) {
            float ov = __shfl_xor(bv, off);
            int oi = __shfl_xor(bi, off);
            float ox = __shfl_xor(bx, off);
            float oy = __shfl_xor(by, off);
            float oz = __shfl_xor(bz, off);
            bool t = (ov > bv) || (ov == bv && oi < bi);
            bv = t ? ov : bv; bi = t ? oi : bi;
            bx = t ? ox : bx; by = t ? oy : by; bz = t ? oz : bz;
        }
        if (lane == 0) {
            rv[par][w] = bv; ri[par][w] = bi;
            rx[par][w] = bx; ry[par][w] = by; rz[par][w] = bz;
        }
        __syncthreads();   // single barrier per iter (parity double-buffer)
        float nv = rv[par][0]; int nidx = ri[par][0];
        float nx = rx[par][0], ny = ry[par][0], nz = rz[par][0];
#pragma unroll
        for (int w2 = 1; w2 < 8; ++w2) {
            float v2 = rv[par][w2]; int i2 = ri[par][w2];
            bool t = (v2 > nv) || (v2 == nv && i2 < nidx);
            nv = t ? v2 : nv; nidx = t ? i2 : nidx;
            nx = t ? rx[par][w2] : nx; ny = t ? ry[par][w2] : ny; nz = t ? rz[par][w2] : nz;
        }
        lx = nx; ly = ny; lz = nz;
        if (tid == 0) {
            new_xyz[((size_t)b * SPTS + it) * 3 + 0] = nx;
            new_xyz[((size_t)b * SPTS + it) * 3 + 1] = ny;
            new_xyz[((size_t)b * SPTS + it) * 3 + 2] = nz;
        }
    }
}

// ---------------- KNN (one wave per (q,set) task) ----------------
__device__ void knn_task(const float* __restrict__ pts, const float* __restrict__ new_xyz,
                         int q, int* __restrict__ out, int lane) {
#pragma clang fp contract(off)
    float q0 = new_xyz[q * 3 + 0];
    float q1 = new_xyz[q * 3 + 1];
    float q2 = new_xyz[q * 3 + 2];
    float qq = q0 * q0 + q1 * q1;
    qq = qq + q2 * q2;

    float bd[12];
    int bi[12];
#pragma unroll
    for (int j = 0; j < 12; ++j) { bd[j] = 1e30f; bi[j] = 0x7fffffff; }

    for (int i = 0; i < NPTS / 64; ++i) {
        int p = i * 64 + lane;
        float p0 = pts[p * 3 + 0], p1 = pts[p * 3 + 1], p2 = pts[p * 3 + 2];
        float pp = p0 * p0 + p1 * p1; pp = pp + p2 * p2;
        float dot = q0 * p0 + q1 * p1; dot = dot + q2 * p2;
        float d = (qq - 2.0f * dot) + pp;  // reference's expanded form
        if (d < bd[11]) {
#pragma unroll
            for (int j = 11; j > 0; --j) {
                bool keep = (d >= bd[j]);
                float sh = (d >= bd[j - 1]) ? d : bd[j - 1];
                int si_ = (d >= bd[j - 1]) ? p : bi[j - 1];
                bd[j] = keep ? bd[j] : sh;
                bi[j] = keep ? bi[j] : si_;
            }
            if (d < bd[0]) { bd[0] = d; bi[0] = p; }
        }
    }

    // 12 rounds of lexicographic wave arg-min pop
    for (int r = 0; r < KNN_K; ++r) {
        float cv = bd[0];
        int ci = bi[0];
#pragma unroll
        for (int off = 1; off < 64; off <<= 1) {
            float ov = __shfl_xor(cv, off);
            int oi = __shfl_xor(ci, off);
            if (ov < cv || (ov == cv && oi < ci)) { cv = ov; ci = oi; }
        }
        if (lane == 0) out[r] = ci;
        if (ci == bi[0]) {  // winner lane pops (each lane's candidate set disjoint)
#pragma unroll
            for (int j = 0; j < 11; ++j) { bd[j] = bd[j + 1]; bi[j] = bi[j + 1]; }
            bd[11] = 1e30f;
            bi[11] = 0x7fffffff;
        }
    }
}

// ---------------- GEMM task (BM=128 rows / 8 waves of 2Mx4N, BN=256) ----------------
template <int KD>
__device__ void gemm_task(int bid, int w, int lane,
                          const ushort_t* __restrict__ A, const ushort_t* __restrict__ Wb,
                          const float* __restrict__ bias, const float* __restrict__ gamma,
                          const float* __restrict__ beta, const float* __restrict__ mean,
                          const float* __restrict__ var, float* __restrict__ out) {
    int mblk = bid & 63, nblk = bid >> 6;
    int wm = w >> 2, wn = w & 3;
    int lrow = lane & 15, kgrp = lane >> 4;
    int pbase = mblk * 8 + wm * 4;            // point index base (4 points per wave)
    int obase = nblk * 256 + wn * 64;         // output-channel base (64 per wave)

    f32x4 acc[4][4];
#pragma unroll
    for (int mi = 0; mi < 4; ++mi)
#pragma unroll
        for (int ni = 0; ni < 4; ++ni) {
            f32x4 z = {0.f, 0.f, 0.f, 0.f};
            acc[mi][ni] = z;
        }

    for (int kk = 0; kk < KD / 32; ++kk) {
        int k0 = kk * 32 + kgrp * 8;
        bf16x8 a[4];
#pragma unroll
        for (int mi = 0; mi < 4; ++mi) {
            const ushort_t* ap = A + ((size_t)(pbase + mi) * 16 + lrow) * KD + k0;
            a[mi] = *reinterpret_cast<const bf16x8*>(ap);
        }
#pragma unroll
        for (int ni = 0; ni < 4; ++ni) {
            const ushort_t* bp = Wb + (size_t)(obase + ni * 16 + lrow) * KD + k0;
            bf16x8 bv = *reinterpret_cast<const bf16x8*>(bp);
#pragma unroll
            for (int mi = 0; mi < 4; ++mi)
                acc[mi][ni] = __builtin_amdgcn_mfma_f32_16x16x32_bf16(a[mi], bv, acc[mi][ni], 0, 0, 0);
        }
    }

    // epilogue: BN + ReLU + max over k rows (12 valid of 16)
#pragma unroll
    for (int ni = 0; ni < 4; ++ni) {
        int o = obase + ni * 16 + lrow;
        float sc = gamma[o] / sqrtf(var[o] + 1e-5f);
        float sh = (bias[o] - mean[o]) * sc + beta[o];
#pragma unroll
        for (int mi = 0; mi < 4; ++mi) {
            float m;
            if (kgrp < 3) {
                float y0 = fmaxf(acc[mi][ni][0] * sc + sh, 0.0f);
                float y1 = fmaxf(acc[mi][ni][1] * sc + sh, 0.0f);
                float y2 = fmaxf(acc[mi][ni][2] * sc + sh, 0.0f);
                float y3 = fmaxf(acc[mi][ni][3] * sc + sh, 0.0f);
                m = fmaxf(fmaxf(y0, y1), fmaxf(y2, y3));
            } else {
                m = -1e30f;  // pad rows 12..15
            }
            m = fmaxf(m, __shfl_xor(m, 16));
            m = fmaxf(m, __shfl_xor(m, 32));
            if (kgrp == 0) out[(size_t)(pbase + mi) * DOUT + o] = m;
        }
    }
}

// ---------------- the mega-kernel ----------------
__global__ __launch_bounds__(NTHR, 2) void mega_kernel(Params P) {
    __shared__ float rv[2][8], rx[2][8], ry[2][8], rz[2][8];
    __shared__ int ri[2][8];

    cg::grid_group grid = cg::this_grid();
    int bid = blockIdx.x;
    int tid = threadIdx.x;
    int w = tid >> 6, lane = tid & 63;

    // ---- phase 0: FPS (blocks 0-15) || W->bf16 convert (blocks 16-255) ----
    if (bid < 16) {
        fps_phase(P.xyz_t, P.new_xyz, bid, rv, rx, ry, rz, ri);
    } else {
        int lin = (bid - 16) * NTHR + tid;
        const int n4t = (DT * DOUT) / 4;        // 262144
        const int n4s = (DS * DOUT) / 4;        // 65536
        for (int i = lin; i < n4t + n4s; i += 240 * NTHR) {
            if (i < n4t) {
                float4 v = reinterpret_cast<const float4*>(P.Wt)[i];
                ushort4 u;
                u.x = f2bf(v.x); u.y = f2bf(v.y); u.z = f2bf(v.z); u.w = f2bf(v.w);
                reinterpret_cast<ushort4*>(P.Wb_t)[i] = u;
            } else {
                int i2 = i - n4t;
                float4 v = reinterpret_cast<const float4*>(P.Ws)[i2];
                ushort4 u;
                u.x = f2bf(v.x); u.y = f2bf(v.y); u.z = f2bf(v.z); u.w = f2bf(v.w);
                reinterpret_cast<ushort4*>(P.Wb_s)[i2] = u;
            }
        }
    }
    __threadfence();
    grid.sync();

    // ---- phase 1: KNN, 1 wave per task; tasks: 0..511 = s, 512..1023 = t ----
    {
        int gw = bid * 8 + w;   // 0..2047
        if (gw < 1024) {
            int q = gw & 511;
            int set = gw >> 9;
            int b = q >> 5;
            const float* pts = (set ? P.xyz_t : P.xyz_s) + (size_t)b * NPTS * 3;
            int* out = (set ? P.idx_t : P.idx_s) + q * KNN_K;
            knn_task(pts, P.new_xyz, q, out, lane);
        }
    }
    __threadfence();
    grid.sync();

    // ---- phase 2: gather -> bf16 A matrices (rows 0..8191 = t, 8192..16383 = s) ----
    {
        int gw = bid * 8 + w;   // 0..2047
        for (int rt = gw; rt < 16384; rt += 2048) {
            bool is_t = rt < 8192;
            int row = is_t ? rt : rt - 8192;
            int p = row >> 4, k = row & 15;
            int D = is_t ? DT : DS;
            const float* feat = is_t ? P.feature_t : P.feature_s;
            const int* idx = is_t ? P.idx_t : P.idx_s;
            ushort_t* A = is_t ? P.A_t : P.A_s;
            ushort4* a4 = reinterpret_cast<ushort4*>(A + (size_t)row * D);
            int n4 = D >> 2;
            if (k < KNN_K) {
                int src = idx[p * KNN_K + k];
                int b = p >> 5;
                const float4* f4 = reinterpret_cast<const float4*>(feat + ((size_t)b * NPTS + src) * D);
                for (int j = lane; j < n4; j += 64) {
                    float4 v = f4[j];
                    ushort4 u;
                    u.x = f2bf(v.x); u.y = f2bf(v.y); u.z = f2bf(v.z); u.w = f2bf(v.w);
                    a4[j] = u;
                }
            } else {
                ushort4 z; z.x = 0; z.y = 0; z.z = 0; z.w = 0;
                for (int j = lane; j < n4; j += 64) a4[j] = z;
            }
        }
    }
    __threadfence();
    grid.sync();

    // ---- phase 3: both GEMMs (one s-task and one t-task per block) ----
    gemm_task<DS>(bid, w, lane, P.A_s, P.Wb_s, P.bias_s, P.gamma_s, P.beta_s,
                  P.mean_s, P.var_s, P.out);
    gemm_task<DT>(bid, w, lane, P.A_t, P.Wb_t, P.bias_t, P.gamma_t, P.beta_t,
                  P.mean_t, P.var_t, P.out + (size_t)512 * 1024);
}

extern "C" void kernel_launch(void* const* d_in, const int* in_sizes, int n_in,
                              void* d_out, int out_size, void* d_ws, size_t ws_size,
                              hipStream_t stream) {
    char* ws = (char*)d_ws;
    Params P;
    P.feature_s = (const float*)d_in[0];
    P.xyz_s     = (const float*)d_in[1];
    P.feature_t = (const float*)d_in[2];
    P.xyz_t     = (const float*)d_in[3];
    P.Ws        = (const float*)d_in[4];
    P.bias_s    = (const float*)d_in[5];
    P.gamma_s   = (const float*)d_in[6];
    P.beta_s    = (const float*)d_in[7];
    P.mean_s    = (const float*)d_in[8];
    P.var_s     = (const float*)d_in[9];
    P.Wt        = (const float*)d_in[10];
    P.bias_t    = (const float*)d_in[11];
    P.gamma_t   = (const float*)d_in[12];
    P.beta_t    = (const float*)d_in[13];
    P.mean_t    = (const float*)d_in[14];
    P.var_t     = (const float*)d_in[15];
    P.out       = (float*)d_out;
    P.new_xyz   = (float*)(ws + 0);
    P.idx_s     = (int*)(ws + 8192);
    P.idx_t     = (int*)(ws + 32768);
    P.Wb_s      = (ushort_t*)(ws + 57344);
    P.Wb_t      = (ushort_t*)(ws + 581632);
    P.A_s       = (ushort_t*)(ws + 2678784);
    P.A_t       = (ushort_t*)(ws + 6873088);

    void* args[] = {(void*)&P};
    hipLaunchCooperativeKernel((const void*)mega_kernel, dim3(NBLK), dim3(NTHR),
                               args, 0, stream);
}

// Round 5
// 192.658 us; speedup vs baseline: 2.0994x; 2.0994x over previous
//
#include <hip/hip_runtime.h>
#include <hip/hip_bf16.h>

// RelationCos pipeline in 3 kernels (kernel boundaries = the only global syncs):
//   K1: FPS (blocks 0-15, one batch each) || W->bf16 convert (blocks 16-255)
//   K2: per-query KNN (both sets in parallel, 8 waves) + gather -> bf16 A (LDS idx)
//   K3: both MFMA GEMMs + BN/ReLU/max epilogue (512 blocks: s then t tasks)

#define NPTS 8192
#define SPTS 32
#define KNN_K 12
#define DS 256
#define DT 1024
#define DOUT 1024

typedef float f32x4 __attribute__((ext_vector_type(4)));
typedef __bf16 bf16x8 __attribute__((ext_vector_type(8)));
typedef unsigned short ushort_t;

__device__ __forceinline__ ushort_t f2bf(float f) {
    unsigned int u = __float_as_uint(f);
    u += 0x7fffu + ((u >> 16) & 1u);   // RNE
    return (ushort_t)(u >> 16);
}

// ==================== K1: FPS || W convert ====================
__global__ __launch_bounds__(512) void fps_convw_kernel(const float* __restrict__ xyz,
                                                        float* __restrict__ new_xyz,
                                                        const float* __restrict__ Wt,
                                                        ushort_t* __restrict__ Wb_t,
                                                        const float* __restrict__ Ws,
                                                        ushort_t* __restrict__ Wb_s) {
    int bid = blockIdx.x;
    int tid = threadIdx.x;

    if (bid >= 16) {
        // W -> bf16 (240 blocks)
        int lin = (bid - 16) * 512 + tid;
        const int n4t = (DT * DOUT) / 4;   // 262144
        const int n4s = (DS * DOUT) / 4;   // 65536
        for (int i = lin; i < n4t + n4s; i += 240 * 512) {
            if (i < n4t) {
                float4 v = reinterpret_cast<const float4*>(Wt)[i];
                ushort4 u;
                u.x = f2bf(v.x); u.y = f2bf(v.y); u.z = f2bf(v.z); u.w = f2bf(v.w);
                reinterpret_cast<ushort4*>(Wb_t)[i] = u;
            } else {
                int i2 = i - n4t;
                float4 v = reinterpret_cast<const float4*>(Ws)[i2];
                ushort4 u;
                u.x = f2bf(v.x); u.y = f2bf(v.y); u.z = f2bf(v.z); u.w = f2bf(v.w);
                reinterpret_cast<ushort4*>(Wb_s)[i2] = u;
            }
        }
        return;
    }

    // ---- FPS: one block per batch, 16 pts/lane register-resident ----
    {
#pragma clang fp contract(off)
        int b = bid;
        const float* base = xyz + (size_t)b * NPTS * 3;

        float px[16], py[16], pz[16], dd[16];
#pragma unroll
        for (int i = 0; i < 16; ++i) {
            int p = tid + i * 512;
            px[i] = base[p * 3 + 0];
            py[i] = base[p * 3 + 1];
            pz[i] = base[p * 3 + 2];
            dd[i] = 1e10f;
        }

        __shared__ float rv[2][8], rx[2][8], ry[2][8], rz[2][8];
        __shared__ int ri[2][8];

        float lx = base[0], ly = base[1], lz = base[2];
        if (tid == 0) {
            new_xyz[((size_t)b * SPTS + 0) * 3 + 0] = lx;
            new_xyz[((size_t)b * SPTS + 0) * 3 + 1] = ly;
            new_xyz[((size_t)b * SPTS + 0) * 3 + 2] = lz;
        }

        int w = tid >> 6, lane = tid & 63;
        for (int it = 1; it < SPTS; ++it) {
            int par = it & 1;
            float bv = -1.0f, bx = 0.f, by = 0.f, bz = 0.f;
            int bi = NPTS;
#pragma unroll
            for (int i = 0; i < 16; ++i) {
                float dx = px[i] - lx, dy = py[i] - ly, dz = pz[i] - lz;
                float d = dx * dx + dy * dy;
                d = d + dz * dz;
                float nd = fminf(dd[i], d);
                dd[i] = nd;
                bool t = nd > bv;  // strict >: first occurrence (in-lane ascending index)
                bv = t ? nd : bv;
                bi = t ? (tid + i * 512) : bi;
                bx = t ? px[i] : bx;
                by = t ? py[i] : by;
                bz = t ? pz[i] : bz;
            }
#pragma unroll
            for (int off = 1; off < 64; off <<= 1) {
                float ov = __shfl_xor(bv, off);
                int oi = __shfl_xor(bi, off);
                float ox = __shfl_xor(bx, off);
                float oy = __shfl_xor(by, off);
                float oz = __shfl_xor(bz, off);
                bool t = (ov > bv) || (ov == bv && oi < bi);
                bv = t ? ov : bv; bi = t ? oi : bi;
                bx = t ? ox : bx; by = t ? oy : by; bz = t ? oz : bz;
            }
            if (lane == 0) {
                rv[par][w] = bv; ri[par][w] = bi;
                rx[par][w] = bx; ry[par][w] = by; rz[par][w] = bz;
            }
            __syncthreads();   // one barrier per iter (parity double-buffer)
            float nv = rv[par][0]; int nidx = ri[par][0];
            float nx = rx[par][0], ny = ry[par][0], nz = rz[par][0];
#pragma unroll
            for (int w2 = 1; w2 < 8; ++w2) {
                float v2 = rv[par][w2]; int i2 = ri[par][w2];
                bool t = (v2 > nv) || (v2 == nv && i2 < nidx);
                nv = t ? v2 : nv; nidx = t ? i2 : nidx;
                nx = t ? rx[par][w2] : nx; ny = t ? ry[par][w2] : ny; nz = t ? rz[par][w2] : nz;
            }
            lx = nx; ly = ny; lz = nz;
            if (tid == 0) {
                new_xyz[((size_t)b * SPTS + it) * 3 + 0] = nx;
                new_xyz[((size_t)b * SPTS + it) * 3 + 1] = ny;
                new_xyz[((size_t)b * SPTS + it) * 3 + 2] = nz;
            }
        }
    }
}

// ==================== K2: KNN (both sets) + gather ====================
// 512 blocks (one per query) x 512 threads. Waves 0-3: set s; waves 4-7: set t.
// Each wave scans 2048 points -> per-lane reg top-12 -> per-wave 12-round pop ->
// 48-candidate merge per set -> indices stay in LDS -> same block gathers A rows.
__global__ __launch_bounds__(512) void knn_gather_kernel(const float* __restrict__ xyz_s,
                                                         const float* __restrict__ xyz_t,
                                                         const float* __restrict__ new_xyz,
                                                         const float* __restrict__ feature_s,
                                                         const float* __restrict__ feature_t,
                                                         ushort_t* __restrict__ A_s,
                                                         ushort_t* __restrict__ A_t) {
#pragma clang fp contract(off)
    int q = blockIdx.x;
    int tid = threadIdx.x;
    int w = tid >> 6, lane = tid & 63;
    int set = w >> 2;        // 0 = s, 1 = t
    int sw = w & 3;          // wave within set
    int b = q >> 5;

    const float* pts = (set ? xyz_t : xyz_s) + (size_t)b * NPTS * 3;

    float q0 = new_xyz[q * 3 + 0];
    float q1 = new_xyz[q * 3 + 1];
    float q2 = new_xyz[q * 3 + 2];
    float qq = q0 * q0 + q1 * q1;
    qq = qq + q2 * q2;

    float bd[12];
    int bi[12];
#pragma unroll
    for (int j = 0; j < 12; ++j) { bd[j] = 1e30f; bi[j] = 0x7fffffff; }

    for (int i = 0; i < 2048 / 64; ++i) {
        int p = sw * 2048 + i * 64 + lane;  // in-lane ascending global index
        float p0 = pts[p * 3 + 0], p1 = pts[p * 3 + 1], p2 = pts[p * 3 + 2];
        float pp = p0 * p0 + p1 * p1; pp = pp + p2 * p2;
        float dot = q0 * p0 + q1 * p1; dot = dot + q2 * p2;
        float d = (qq - 2.0f * dot) + pp;  // reference's expanded form
        if (d < bd[11]) {
#pragma unroll
            for (int j = 11; j > 0; --j) {
                bool keep = (d >= bd[j]);
                float sh = (d >= bd[j - 1]) ? d : bd[j - 1];
                int si_ = (d >= bd[j - 1]) ? p : bi[j - 1];
                bd[j] = keep ? bd[j] : sh;
                bi[j] = keep ? bi[j] : si_;
            }
            if (d < bd[0]) { bd[0] = d; bi[0] = p; }
        }
    }

    __shared__ float sd[2][48];
    __shared__ int si[2][48];
    __shared__ int kidx[2][KNN_K];

    // per-wave: 12 rounds of lexicographic wave arg-min pop -> LDS
#pragma unroll
    for (int r = 0; r < KNN_K; ++r) {
        float cv = bd[0];
        int ci = bi[0];
#pragma unroll
        for (int off = 1; off < 64; off <<= 1) {
            float ov = __shfl_xor(cv, off);
            int oi = __shfl_xor(ci, off);
            if (ov < cv || (ov == cv && oi < ci)) { cv = ov; ci = oi; }
        }
        if (lane == 0) { sd[set][sw * KNN_K + r] = cv; si[set][sw * KNN_K + r] = ci; }
        if (ci == bi[0]) {  // winner lane pops its head (indices unique per wave range)
#pragma unroll
            for (int j = 0; j < 11; ++j) { bd[j] = bd[j + 1]; bi[j] = bi[j + 1]; }
            bd[11] = 1e30f;
            bi[11] = 0x7fffffff;
        }
    }
    __syncthreads();

    // waves 0 and 4 merge their set's 48 candidates
    if (sw == 0) {
        float cd = (lane < 48) ? sd[set][lane] : 1e30f;
        int cix = (lane < 48) ? si[set][lane] : 0x7fffffff;
#pragma unroll
        for (int r = 0; r < KNN_K; ++r) {
            float mv = cd;
            int mi = cix;
#pragma unroll
            for (int off = 1; off < 64; off <<= 1) {
                float ov = __shfl_xor(mv, off);
                int oi = __shfl_xor(mi, off);
                if (ov < mv || (ov == mv && oi < mi)) { mv = ov; mi = oi; }
            }
            if (lane == 0) kidx[set][r] = mi;
            if (cix == mi) cd = 1e30f;  // pop (indices unique across disjoint ranges)
        }
    }
    __syncthreads();

    // ---- gather: 32 virtual rows (0..15 = t rows, 16..31 = s rows), interleaved ----
#pragma unroll
    for (int j = 0; j < 4; ++j) {
        int vr = j * 8 + w;          // balance: each wave gets 2 t-rows + 2 s-rows
        bool is_t = vr < 16;
        int k = vr & 15;
        int D = is_t ? DT : DS;
        int n4 = D >> 2;
        ushort_t* A = is_t ? A_t : A_s;
        ushort4* a4 = reinterpret_cast<ushort4*>(A + ((size_t)q * 16 + k) * D);
        if (k < KNN_K) {
            int src = kidx[is_t ? 1 : 0][k];
            const float* feat = is_t ? feature_t : feature_s;
            const float4* f4 = reinterpret_cast<const float4*>(feat + ((size_t)b * NPTS + src) * D);
            for (int jj = lane; jj < n4; jj += 64) {
                float4 v = f4[jj];
                ushort4 u;
                u.x = f2bf(v.x); u.y = f2bf(v.y); u.z = f2bf(v.z); u.w = f2bf(v.w);
                a4[jj] = u;
            }
        } else {
            ushort4 z; z.x = 0; z.y = 0; z.z = 0; z.w = 0;
            for (int jj = lane; jj < n4; jj += 64) a4[jj] = z;
        }
    }
}

// ==================== K3: both GEMMs ====================
// Per task: 4 waves; M-tile = 8 points (128 rows), N-tile = 256 (64/wave).
// A frag: lane holds A[m=lane&15][k=(lane>>4)*8+e]; C/D: col=lane&15, row=(lane>>4)*4+reg.
template <int KD>
__device__ __forceinline__ void gemm_task(int id, int w, int lane,
                                          const ushort_t* __restrict__ A,
                                          const ushort_t* __restrict__ Wb,
                                          const float* __restrict__ bias,
                                          const float* __restrict__ gamma,
                                          const float* __restrict__ beta,
                                          const float* __restrict__ mean,
                                          const float* __restrict__ var,
                                          float* __restrict__ out) {
    int mblk = id & 63, nblk = id >> 6;
    int p0 = mblk * 8;
    int o_wave = nblk * 256 + w * 64;
    int lrow = lane & 15, kgrp = lane >> 4;

    f32x4 acc[8][4];
#pragma unroll
    for (int mi = 0; mi < 8; ++mi)
#pragma unroll
        for (int ni = 0; ni < 4; ++ni) {
            f32x4 z = {0.f, 0.f, 0.f, 0.f};
            acc[mi][ni] = z;
        }

    for (int kk = 0; kk < KD / 32; ++kk) {
        int k0 = kk * 32 + kgrp * 8;
        bf16x8 a[8];
#pragma unroll
        for (int mi = 0; mi < 8; ++mi) {
            const ushort_t* ap = A + ((size_t)(p0 + mi) * 16 + lrow) * KD + k0;
            a[mi] = *reinterpret_cast<const bf16x8*>(ap);
        }
#pragma unroll
        for (int ni = 0; ni < 4; ++ni) {
            const ushort_t* bp = Wb + (size_t)(o_wave + ni * 16 + lrow) * KD + k0;
            bf16x8 bf = *reinterpret_cast<const bf16x8*>(bp);
#pragma unroll
            for (int mi = 0; mi < 8; ++mi)
                acc[mi][ni] = __builtin_amdgcn_mfma_f32_16x16x32_bf16(a[mi], bf, acc[mi][ni], 0, 0, 0);
        }
    }

#pragma unroll
    for (int ni = 0; ni < 4; ++ni) {
        int o = o_wave + ni * 16 + lrow;
        float sc = gamma[o] / sqrtf(var[o] + 1e-5f);
        float sh = (bias[o] - mean[o]) * sc + beta[o];
#pragma unroll
        for (int mi = 0; mi < 8; ++mi) {
            float m;
            if (kgrp < 3) {
                float y0 = fmaxf(acc[mi][ni][0] * sc + sh, 0.0f);
                float y1 = fmaxf(acc[mi][ni][1] * sc + sh, 0.0f);
                float y2 = fmaxf(acc[mi][ni][2] * sc + sh, 0.0f);
                float y3 = fmaxf(acc[mi][ni][3] * sc + sh, 0.0f);
                m = fmaxf(fmaxf(y0, y1), fmaxf(y2, y3));
            } else {
                m = -1e30f;  // pad rows 12..15
            }
            m = fmaxf(m, __shfl_xor(m, 16));
            m = fmaxf(m, __shfl_xor(m, 32));
            if (kgrp == 0) out[(size_t)(p0 + mi) * DOUT + o] = m;
        }
    }
}

__global__ __launch_bounds__(256) void gemm_kernel(const ushort_t* __restrict__ A_s,
                                                   const ushort_t* __restrict__ Wb_s,
                                                   const ushort_t* __restrict__ A_t,
                                                   const ushort_t* __restrict__ Wb_t,
                                                   const float* __restrict__ bias_s,
                                                   const float* __restrict__ gamma_s,
                                                   const float* __restrict__ beta_s,
                                                   const float* __restrict__ mean_s,
                                                   const float* __restrict__ var_s,
                                                   const float* __restrict__ bias_t,
                                                   const float* __restrict__ gamma_t,
                                                   const float* __restrict__ beta_t,
                                                   const float* __restrict__ mean_t,
                                                   const float* __restrict__ var_t,
                                                   float* __restrict__ out) {
    int bid = blockIdx.x;
    int tid = threadIdx.x;
    int w = tid >> 6, lane = tid & 63;
    if (bid < 256) {
        gemm_task<DS>(bid, w, lane, A_s, Wb_s, bias_s, gamma_s, beta_s, mean_s, var_s, out);
    } else {
        gemm_task<DT>(bid - 256, w, lane, A_t, Wb_t, bias_t, gamma_t, beta_t, mean_t, var_t,
                      out + (size_t)512 * 1024);
    }
}

extern "C" void kernel_launch(void* const* d_in, const int* in_sizes, int n_in,
                              void* d_out, int out_size, void* d_ws, size_t ws_size,
                              hipStream_t stream) {
    const float* feature_s = (const float*)d_in[0];
    const float* xyz_s     = (const float*)d_in[1];
    const float* feature_t = (const float*)d_in[2];
    const float* xyz_t     = (const float*)d_in[3];
    const float* Ws        = (const float*)d_in[4];
    const float* bias_s    = (const float*)d_in[5];
    const float* gamma_s   = (const float*)d_in[6];
    const float* beta_s    = (const float*)d_in[7];
    const float* mean_s    = (const float*)d_in[8];
    const float* var_s     = (const float*)d_in[9];
    const float* Wt        = (const float*)d_in[10];
    const float* bias_t    = (const float*)d_in[11];
    const float* gamma_t   = (const float*)d_in[12];
    const float* beta_t    = (const float*)d_in[13];
    const float* mean_t    = (const float*)d_in[14];
    const float* var_t     = (const float*)d_in[15];
    float* out = (float*)d_out;

    char* ws = (char*)d_ws;
    float* new_xyz  = (float*)(ws + 0);
    ushort_t* Wb_s  = (ushort_t*)(ws + 57344);
    ushort_t* Wb_t  = (ushort_t*)(ws + 581632);
    ushort_t* A_s   = (ushort_t*)(ws + 2678784);
    ushort_t* A_t   = (ushort_t*)(ws + 6873088);

    fps_convw_kernel<<<256, 512, 0, stream>>>(xyz_t, new_xyz, Wt, Wb_t, Ws, Wb_s);
    knn_gather_kernel<<<512, 512, 0, stream>>>(xyz_s, xyz_t, new_xyz,
                                               feature_s, feature_t, A_s, A_t);
    gemm_kernel<<<512, 256, 0, stream>>>(A_s, Wb_s, A_t, Wb_t,
                                         bias_s, gamma_s, beta_s, mean_s, var_s,
                                         bias_t, gamma_t, beta_t, mean_t, var_t, out);
}

// Round 6
// 185.234 us; speedup vs baseline: 2.1835x; 1.0401x over previous
//
#include <hip/hip_runtime.h>
#include <hip/hip_bf16.h>

// RelationCos pipeline in 3 kernels:
//   K1: FPS (blocks 0-15) || W->bf16 convert (blocks 16-255)
//   K2: KNN only (both sets, 8 waves/query) -> kidx in ws
//   K3: gather-FUSED MFMA GEMM: block = 4 queries (64 rows) x 1024 cols, 8 waves;
//       per K-step stage 64x32 f32 slab -> bf16 LDS (double-buffered), B direct bf16.
//       Each feature row read exactly once from HBM; no A-matrix round-trip.

#define NPTS 8192
#define SPTS 32
#define KNN_K 12
#define DS 256
#define DT 1024
#define DOUT 1024

typedef float f32x4 __attribute__((ext_vector_type(4)));
typedef __bf16 bf16x8 __attribute__((ext_vector_type(8)));
typedef unsigned short ushort_t;

__device__ __forceinline__ ushort_t f2bf(float f) {
    unsigned int u = __float_as_uint(f);
    u += 0x7fffu + ((u >> 16) & 1u);   // RNE
    return (ushort_t)(u >> 16);
}

// ==================== K1: FPS || W convert ====================
__global__ __launch_bounds__(512) void fps_convw_kernel(const float* __restrict__ xyz,
                                                        float* __restrict__ new_xyz,
                                                        const float* __restrict__ Wt,
                                                        ushort_t* __restrict__ Wb_t,
                                                        const float* __restrict__ Ws,
                                                        ushort_t* __restrict__ Wb_s) {
    int bid = blockIdx.x;
    int tid = threadIdx.x;

    if (bid >= 16) {
        // W -> bf16 (240 blocks)
        int lin = (bid - 16) * 512 + tid;
        const int n4t = (DT * DOUT) / 4;   // 262144
        const int n4s = (DS * DOUT) / 4;   // 65536
        for (int i = lin; i < n4t + n4s; i += 240 * 512) {
            if (i < n4t) {
                float4 v = reinterpret_cast<const float4*>(Wt)[i];
                ushort4 u;
                u.x = f2bf(v.x); u.y = f2bf(v.y); u.z = f2bf(v.z); u.w = f2bf(v.w);
                reinterpret_cast<ushort4*>(Wb_t)[i] = u;
            } else {
                int i2 = i - n4t;
                float4 v = reinterpret_cast<const float4*>(Ws)[i2];
                ushort4 u;
                u.x = f2bf(v.x); u.y = f2bf(v.y); u.z = f2bf(v.z); u.w = f2bf(v.w);
                reinterpret_cast<ushort4*>(Wb_s)[i2] = u;
            }
        }
        return;
    }

    // ---- FPS: one block per batch, 16 pts/lane register-resident ----
    {
#pragma clang fp contract(off)
        int b = bid;
        const float* base = xyz + (size_t)b * NPTS * 3;

        float px[16], py[16], pz[16], dd[16];
#pragma unroll
        for (int i = 0; i < 16; ++i) {
            int p = tid + i * 512;
            px[i] = base[p * 3 + 0];
            py[i] = base[p * 3 + 1];
            pz[i] = base[p * 3 + 2];
            dd[i] = 1e10f;
        }

        __shared__ float rv[2][8], rx[2][8], ry[2][8], rz[2][8];
        __shared__ int ri[2][8];

        float lx = base[0], ly = base[1], lz = base[2];
        if (tid == 0) {
            new_xyz[((size_t)b * SPTS + 0) * 3 + 0] = lx;
            new_xyz[((size_t)b * SPTS + 0) * 3 + 1] = ly;
            new_xyz[((size_t)b * SPTS + 0) * 3 + 2] = lz;
        }

        int w = tid >> 6, lane = tid & 63;
        for (int it = 1; it < SPTS; ++it) {
            int par = it & 1;
            float bv = -1.0f, bx = 0.f, by = 0.f, bz = 0.f;
            int bi = NPTS;
#pragma unroll
            for (int i = 0; i < 16; ++i) {
                float dx = px[i] - lx, dy = py[i] - ly, dz = pz[i] - lz;
                float d = dx * dx + dy * dy;
                d = d + dz * dz;
                float nd = fminf(dd[i], d);
                dd[i] = nd;
                bool t = nd > bv;  // strict >: first occurrence (in-lane ascending index)
                bv = t ? nd : bv;
                bi = t ? (tid + i * 512) : bi;
                bx = t ? px[i] : bx;
                by = t ? py[i] : by;
                bz = t ? pz[i] : bz;
            }
#pragma unroll
            for (int off = 1; off < 64; off <<= 1) {
                float ov = __shfl_xor(bv, off);
                int oi = __shfl_xor(bi, off);
                float ox = __shfl_xor(bx, off);
                float oy = __shfl_xor(by, off);
                float oz = __shfl_xor(bz, off);
                bool t = (ov > bv) || (ov == bv && oi < bi);
                bv = t ? ov : bv; bi = t ? oi : bi;
                bx = t ? ox : bx; by = t ? oy : by; bz = t ? oz : bz;
            }
            if (lane == 0) {
                rv[par][w] = bv; ri[par][w] = bi;
                rx[par][w] = bx; ry[par][w] = by; rz[par][w] = bz;
            }
            __syncthreads();   // one barrier per iter (parity double-buffer)
            float nv = rv[par][0]; int nidx = ri[par][0];
            float nx = rx[par][0], ny = ry[par][0], nz = rz[par][0];
#pragma unroll
            for (int w2 = 1; w2 < 8; ++w2) {
                float v2 = rv[par][w2]; int i2 = ri[par][w2];
                bool t = (v2 > nv) || (v2 == nv && i2 < nidx);
                nv = t ? v2 : nv; nidx = t ? i2 : nidx;
                nx = t ? rx[par][w2] : nx; ny = t ? ry[par][w2] : ny; nz = t ? rz[par][w2] : nz;
            }
            lx = nx; ly = ny; lz = nz;
            if (tid == 0) {
                new_xyz[((size_t)b * SPTS + it) * 3 + 0] = nx;
                new_xyz[((size_t)b * SPTS + it) * 3 + 1] = ny;
                new_xyz[((size_t)b * SPTS + it) * 3 + 2] = nz;
            }
        }
    }
}

// ==================== K2: KNN only ====================
// 512 blocks (one per query) x 512 threads. Waves 0-3: set s; waves 4-7: set t.
// Per wave scans 2048 points -> reg top-12 -> 12-round pop -> 48-cand merge -> global idx.
__global__ __launch_bounds__(512) void knn_kernel(const float* __restrict__ xyz_s,
                                                  const float* __restrict__ xyz_t,
                                                  const float* __restrict__ new_xyz,
                                                  int* __restrict__ idx_s,
                                                  int* __restrict__ idx_t) {
#pragma clang fp contract(off)
    int q = blockIdx.x;
    int tid = threadIdx.x;
    int w = tid >> 6, lane = tid & 63;
    int set = w >> 2;        // 0 = s, 1 = t
    int sw = w & 3;          // wave within set
    int b = q >> 5;

    const float* pts = (set ? xyz_t : xyz_s) + (size_t)b * NPTS * 3;

    float q0 = new_xyz[q * 3 + 0];
    float q1 = new_xyz[q * 3 + 1];
    float q2 = new_xyz[q * 3 + 2];
    float qq = q0 * q0 + q1 * q1;
    qq = qq + q2 * q2;

    float bd[12];
    int bi[12];
#pragma unroll
    for (int j = 0; j < 12; ++j) { bd[j] = 1e30f; bi[j] = 0x7fffffff; }

    for (int i = 0; i < 2048 / 64; ++i) {
        int p = sw * 2048 + i * 64 + lane;  // in-lane ascending global index
        float p0 = pts[p * 3 + 0], p1 = pts[p * 3 + 1], p2 = pts[p * 3 + 2];
        float pp = p0 * p0 + p1 * p1; pp = pp + p2 * p2;
        float dot = q0 * p0 + q1 * p1; dot = dot + q2 * p2;
        float d = (qq - 2.0f * dot) + pp;  // reference's expanded form
        if (d < bd[11]) {
#pragma unroll
            for (int j = 11; j > 0; --j) {
                bool keep = (d >= bd[j]);
                float sh = (d >= bd[j - 1]) ? d : bd[j - 1];
                int si_ = (d >= bd[j - 1]) ? p : bi[j - 1];
                bd[j] = keep ? bd[j] : sh;
                bi[j] = keep ? bi[j] : si_;
            }
            if (d < bd[0]) { bd[0] = d; bi[0] = p; }
        }
    }

    __shared__ float sd[2][48];
    __shared__ int si[2][48];

    // per-wave: 12 rounds of lexicographic wave arg-min pop -> LDS
#pragma unroll
    for (int r = 0; r < KNN_K; ++r) {
        float cv = bd[0];
        int ci = bi[0];
#pragma unroll
        for (int off = 1; off < 64; off <<= 1) {
            float ov = __shfl_xor(cv, off);
            int oi = __shfl_xor(ci, off);
            if (ov < cv || (ov == cv && oi < ci)) { cv = ov; ci = oi; }
        }
        if (lane == 0) { sd[set][sw * KNN_K + r] = cv; si[set][sw * KNN_K + r] = ci; }
        if (ci == bi[0]) {  // winner lane pops its head (indices unique per wave range)
#pragma unroll
            for (int j = 0; j < 11; ++j) { bd[j] = bd[j + 1]; bi[j] = bi[j + 1]; }
            bd[11] = 1e30f;
            bi[11] = 0x7fffffff;
        }
    }
    __syncthreads();

    // waves 0 and 4 merge their set's 48 candidates -> global
    if (sw == 0) {
        int* outp = (set ? idx_t : idx_s) + q * KNN_K;
        float cd = (lane < 48) ? sd[set][lane] : 1e30f;
        int cix = (lane < 48) ? si[set][lane] : 0x7fffffff;
#pragma unroll
        for (int r = 0; r < KNN_K; ++r) {
            float mv = cd;
            int mi = cix;
#pragma unroll
            for (int off = 1; off < 64; off <<= 1) {
                float ov = __shfl_xor(mv, off);
                int oi = __shfl_xor(mi, off);
                if (ov < mv || (ov == mv && oi < mi)) { mv = ov; mi = oi; }
            }
            if (lane == 0) outp[r] = mi;
            if (cix == mi) cd = 1e30f;  // pop (indices unique across disjoint ranges)
        }
    }
}

// ==================== K3: gather-fused GEMM ====================
// Block = 4 queries (64 rows: 16/query, 12 valid) x all 1024 cols; 8 waves of 64x128.
// Per K-step: stage 64x32 f32 slab -> f2bf -> LDS [64][40] bf16 (double-buffered,
// pad -> 2-way-free banks); B read directly from bf16 Wb (per-wave distinct cols).
// C/D frag: col=lane&15, row=(lane>>4)*4+reg; m-frag mf == query mblk*4+mf.
template <int KD>
__device__ __forceinline__ void gemm_fused(int mblk, const float* __restrict__ feat,
                                           const int* __restrict__ kidx,
                                           const ushort_t* __restrict__ Wb,
                                           const float* __restrict__ bias,
                                           const float* __restrict__ gamma,
                                           const float* __restrict__ beta,
                                           const float* __restrict__ mean,
                                           const float* __restrict__ var,
                                           float* __restrict__ out,
                                           ushort_t (*abuf)[64][40]) {
    const int NK = KD / 32;
    int tid = threadIdx.x;
    int w = tid >> 6, lane = tid & 63;
    int lrow = lane & 15, kgrp = lane >> 4;

    // staging role: 8 threads per row, 4 floats each
    int r = tid >> 3, seg = tid & 7;
    int q = mblk * 4 + (r >> 4);
    int k = r & 15;
    bool valid = (k < KNN_K);
    int b = q >> 5;
    int src = valid ? kidx[q * KNN_K + k] : 0;
    const float* srcp = feat + ((size_t)b * NPTS + src) * KD + seg * 4;

    f32x4 acc[4][8];
#pragma unroll
    for (int mi = 0; mi < 4; ++mi)
#pragma unroll
        for (int ni = 0; ni < 8; ++ni) {
            f32x4 z = {0.f, 0.f, 0.f, 0.f};
            acc[mi][ni] = z;
        }

    // prologue: stage slab 0
    {
        float4 v = {0.f, 0.f, 0.f, 0.f};
        if (valid) v = *reinterpret_cast<const float4*>(srcp);
        ushort4 u;
        u.x = f2bf(v.x); u.y = f2bf(v.y); u.z = f2bf(v.z); u.w = f2bf(v.w);
        *reinterpret_cast<ushort4*>(&abuf[0][r][seg * 4]) = u;
    }
    __syncthreads();

    for (int kk = 0; kk < NK; ++kk) {
        int cur = kk & 1;
        // prefetch next slab into registers (global f32)
        float4 nv = {0.f, 0.f, 0.f, 0.f};
        if (kk + 1 < NK && valid)
            nv = *reinterpret_cast<const float4*>(srcp + (kk + 1) * 32);

        // A frags from LDS
        bf16x8 a[4];
#pragma unroll
        for (int mf = 0; mf < 4; ++mf)
            a[mf] = *reinterpret_cast<const bf16x8*>(&abuf[cur][mf * 16 + lrow][kgrp * 8]);

        // B frags direct from global bf16; 8 n-frags = cols w*128 .. w*128+127
#pragma unroll
        for (int nf = 0; nf < 8; ++nf) {
            int col = w * 128 + nf * 16 + lrow;
            const ushort_t* bp = Wb + (size_t)col * KD + kk * 32 + kgrp * 8;
            bf16x8 bfr = *reinterpret_cast<const bf16x8*>(bp);
#pragma unroll
            for (int mf = 0; mf < 4; ++mf)
                acc[mf][nf] = __builtin_amdgcn_mfma_f32_16x16x32_bf16(a[mf], bfr, acc[mf][nf], 0, 0, 0);
        }

        // write next slab to the other LDS buffer
        if (kk + 1 < NK) {
            ushort4 u;
            u.x = f2bf(nv.x); u.y = f2bf(nv.y); u.z = f2bf(nv.z); u.w = f2bf(nv.w);
            *reinterpret_cast<ushort4*>(&abuf[cur ^ 1][r][seg * 4]) = u;
        }
        __syncthreads();
    }

    // epilogue: BN + ReLU + max over rows 0..11; frag rows = kgrp*4+e
#pragma unroll
    for (int nf = 0; nf < 8; ++nf) {
        int col = w * 128 + nf * 16 + lrow;
        float sc = gamma[col] / sqrtf(var[col] + 1e-5f);
        float sh = (bias[col] - mean[col]) * sc + beta[col];
#pragma unroll
        for (int mf = 0; mf < 4; ++mf) {
            float m;
            if (kgrp < 3) {
                float y0 = fmaxf(acc[mf][nf][0] * sc + sh, 0.0f);
                float y1 = fmaxf(acc[mf][nf][1] * sc + sh, 0.0f);
                float y2 = fmaxf(acc[mf][nf][2] * sc + sh, 0.0f);
                float y3 = fmaxf(acc[mf][nf][3] * sc + sh, 0.0f);
                m = fmaxf(fmaxf(y0, y1), fmaxf(y2, y3));
            } else {
                m = -1e30f;  // pad rows 12..15
            }
            m = fmaxf(m, __shfl_xor(m, 16));
            m = fmaxf(m, __shfl_xor(m, 32));
            if (kgrp == 0) out[(size_t)(mblk * 4 + mf) * DOUT + col] = m;
        }
    }
}

__global__ __launch_bounds__(512, 2) void gemm_fused_kernel(const float* __restrict__ feature_s,
                                                            const float* __restrict__ feature_t,
                                                            const int* __restrict__ idx_s,
                                                            const int* __restrict__ idx_t,
                                                            const ushort_t* __restrict__ Wb_s,
                                                            const ushort_t* __restrict__ Wb_t,
                                                            const float* __restrict__ bias_s,
                                                            const float* __restrict__ gamma_s,
                                                            const float* __restrict__ beta_s,
                                                            const float* __restrict__ mean_s,
                                                            const float* __restrict__ var_s,
                                                            const float* __restrict__ bias_t,
                                                            const float* __restrict__ gamma_t,
                                                            const float* __restrict__ beta_t,
                                                            const float* __restrict__ mean_t,
                                                            const float* __restrict__ var_t,
                                                            float* __restrict__ out) {
    __shared__ ushort_t abuf[2][64][40];
    int bid = blockIdx.x;
    if (bid < 128) {
        gemm_fused<DT>(bid, feature_t, idx_t, Wb_t, bias_t, gamma_t, beta_t, mean_t, var_t,
                       out + (size_t)512 * 1024, abuf);
    } else {
        gemm_fused<DS>(bid - 128, feature_s, idx_s, Wb_s, bias_s, gamma_s, beta_s, mean_s, var_s,
                       out, abuf);
    }
}

extern "C" void kernel_launch(void* const* d_in, const int* in_sizes, int n_in,
                              void* d_out, int out_size, void* d_ws, size_t ws_size,
                              hipStream_t stream) {
    const float* feature_s = (const float*)d_in[0];
    const float* xyz_s     = (const float*)d_in[1];
    const float* feature_t = (const float*)d_in[2];
    const float* xyz_t     = (const float*)d_in[3];
    const float* Ws        = (const float*)d_in[4];
    const float* bias_s    = (const float*)d_in[5];
    const float* gamma_s   = (const float*)d_in[6];
    const float* beta_s    = (const float*)d_in[7];
    const float* mean_s    = (const float*)d_in[8];
    const float* var_s     = (const float*)d_in[9];
    const float* Wt        = (const float*)d_in[10];
    const float* bias_t    = (const float*)d_in[11];
    const float* gamma_t   = (const float*)d_in[12];
    const float* beta_t    = (const float*)d_in[13];
    const float* mean_t    = (const float*)d_in[14];
    const float* var_t     = (const float*)d_in[15];
    float* out = (float*)d_out;

    char* ws = (char*)d_ws;
    float* new_xyz  = (float*)(ws + 0);
    int* idx_s      = (int*)(ws + 8192);
    int* idx_t      = (int*)(ws + 32768);
    ushort_t* Wb_s  = (ushort_t*)(ws + 57344);
    ushort_t* Wb_t  = (ushort_t*)(ws + 581632);

    fps_convw_kernel<<<256, 512, 0, stream>>>(xyz_t, new_xyz, Wt, Wb_t, Ws, Wb_s);
    knn_kernel<<<512, 512, 0, stream>>>(xyz_s, xyz_t, new_xyz, idx_s, idx_t);
    gemm_fused_kernel<<<256, 512, 0, stream>>>(feature_s, feature_t, idx_s, idx_t,
                                               Wb_s, Wb_t,
                                               bias_s, gamma_s, beta_s, mean_s, var_s,
                                               bias_t, gamma_t, beta_t, mean_t, var_t, out);
}

// Round 7
// 155.226 us; speedup vs baseline: 2.6057x; 1.1933x over previous
//
#include <hip/hip_runtime.h>
#include <hip/hip_bf16.h>

// RelationCos pipeline in 2 kernels:
//   K1: FPS (blocks 0-15, packed-u64 argmax + LDS coord table) || W->bf16 (blocks 16-255)
//   K2: per-block fused KNN (own 4 queries, own set, packed-u64 keys) + gather-fused
//       MFMA GEMM (4 queries x 1024 cols, staged bf16 LDS, B direct from bf16 W).

#define NPTS 8192
#define SPTS 32
#define KNN_K 12
#define DS 256
#define DT 1024
#define DOUT 1024

typedef float f32x4 __attribute__((ext_vector_type(4)));
typedef __bf16 bf16x8 __attribute__((ext_vector_type(8)));
typedef unsigned short ushort_t;
typedef unsigned long long u64;

__device__ __forceinline__ ushort_t f2bf(float f) {
    unsigned int u = __float_as_uint(f);
    u += 0x7fffu + ((u >> 16) & 1u);   // RNE
    return (ushort_t)(u >> 16);
}

// ==================== K1: FPS || W convert ====================
__global__ __launch_bounds__(512) void fps_convw_kernel(const float* __restrict__ xyz,
                                                        float* __restrict__ new_xyz,
                                                        const float* __restrict__ Wt,
                                                        ushort_t* __restrict__ Wb_t,
                                                        const float* __restrict__ Ws,
                                                        ushort_t* __restrict__ Wb_s) {
    int bid = blockIdx.x;
    int tid = threadIdx.x;

    if (bid >= 16) {
        // W -> bf16 (240 blocks)
        int lin = (bid - 16) * 512 + tid;
        const int n4t = (DT * DOUT) / 4;   // 262144
        const int n4s = (DS * DOUT) / 4;   // 65536
        for (int i = lin; i < n4t + n4s; i += 240 * 512) {
            if (i < n4t) {
                float4 v = reinterpret_cast<const float4*>(Wt)[i];
                ushort4 u;
                u.x = f2bf(v.x); u.y = f2bf(v.y); u.z = f2bf(v.z); u.w = f2bf(v.w);
                reinterpret_cast<ushort4*>(Wb_t)[i] = u;
            } else {
                int i2 = i - n4t;
                float4 v = reinterpret_cast<const float4*>(Ws)[i2];
                ushort4 u;
                u.x = f2bf(v.x); u.y = f2bf(v.y); u.z = f2bf(v.z); u.w = f2bf(v.w);
                reinterpret_cast<ushort4*>(Wb_s)[i2] = u;
            }
        }
        return;
    }

    // ---- FPS: one block per batch; packed (dist_bits, 8191-idx) u64 argmax ----
    {
#pragma clang fp contract(off)
        int b = bid;
        const float* base = xyz + (size_t)b * NPTS * 3;

        __shared__ float cx[NPTS], cy[NPTS], cz[NPTS];   // 96 KB coord table
        __shared__ u64 rkey[2][8];

        float px[16], py[16], pz[16], dd[16];
#pragma unroll
        for (int i = 0; i < 16; ++i) {
            int p = tid + i * 512;
            px[i] = base[p * 3 + 0];
            py[i] = base[p * 3 + 1];
            pz[i] = base[p * 3 + 2];
            dd[i] = 1e10f;
            cx[p] = px[i]; cy[p] = py[i]; cz[p] = pz[i];
        }

        float lx = base[0], ly = base[1], lz = base[2];
        if (tid == 0) {
            new_xyz[((size_t)b * SPTS + 0) * 3 + 0] = lx;
            new_xyz[((size_t)b * SPTS + 0) * 3 + 1] = ly;
            new_xyz[((size_t)b * SPTS + 0) * 3 + 2] = lz;
        }

        int w = tid >> 6;
        for (int it = 1; it < SPTS; ++it) {
            int par = it & 1;
            u64 bk = 0;
#pragma unroll
            for (int i = 0; i < 16; ++i) {
                float dx = px[i] - lx, dy = py[i] - ly, dz = pz[i] - lz;
                float d = dx * dx + dy * dy;
                d = d + dz * dz;
                float nd = fminf(dd[i], d);
                dd[i] = nd;
                // dist >= 0 always: float bits are order-isomorphic as unsigned.
                // low 32 bits = 8191-idx: on equal dist, larger low = smaller idx (first occurrence)
                u64 kd = ((u64)__float_as_uint(nd) << 32) | (unsigned)(8191 - (tid + i * 512));
                bk = (kd > bk) ? kd : bk;
            }
#pragma unroll
            for (int off = 1; off < 64; off <<= 1) {
                u64 ok = __shfl_xor(bk, off);
                bk = (ok > bk) ? ok : bk;
            }
            if ((tid & 63) == 0) rkey[par][w] = bk;
            __syncthreads();   // one barrier per iter (parity double-buffer); also covers cx fill
            u64 nk = rkey[par][0];
#pragma unroll
            for (int w2 = 1; w2 < 8; ++w2) {
                u64 v2 = rkey[par][w2];
                nk = (v2 > nk) ? v2 : nk;
            }
            int idx = 8191 - (int)(unsigned)(nk & 0xFFFFFFFFull);
            lx = cx[idx]; ly = cy[idx]; lz = cz[idx];   // LDS broadcast (same address)
            if (tid == 0) {
                new_xyz[((size_t)b * SPTS + it) * 3 + 0] = lx;
                new_xyz[((size_t)b * SPTS + it) * 3 + 1] = ly;
                new_xyz[((size_t)b * SPTS + it) * 3 + 2] = lz;
            }
        }
    }
}

// ==================== K2: fused KNN + GEMM ====================

// KNN phase: 4 queries per block, 2 waves per query (4096 pts each).
// Packed key = (monotone(bits(d)) << 32) | idx ; min-lex == (d, idx) lex min.
__device__ __forceinline__ void knn_phase(const float* __restrict__ pts,
                                          const float* __restrict__ new_xyz,
                                          int q0, u64 (*sd)[KNN_K], int (*kidx)[KNN_K]) {
#pragma clang fp contract(off)
    int tid = threadIdx.x;
    int w = tid >> 6, lane = tid & 63;
    int qi = w >> 1, sw = w & 1;
    int q = q0 + qi;

    float qx = new_xyz[q * 3 + 0];
    float qy = new_xyz[q * 3 + 1];
    float qz = new_xyz[q * 3 + 2];
    float qq = qx * qx + qy * qy;
    qq = qq + qz * qz;

    u64 bd[12];
#pragma unroll
    for (int j = 0; j < 12; ++j) bd[j] = ~0ULL;

    for (int i = 0; i < 4096 / 64; ++i) {
        int p = sw * 4096 + i * 64 + lane;
        float p0 = pts[p * 3 + 0], p1 = pts[p * 3 + 1], p2 = pts[p * 3 + 2];
        float pp = p0 * p0 + p1 * p1; pp = pp + p2 * p2;
        float dot = qx * p0 + qy * p1; dot = dot + qz * p2;
        float d = (qq - 2.0f * dot) + pp;  // reference's expanded form (can be negative)
        unsigned u = __float_as_uint(d);
        u = (u & 0x80000000u) ? ~u : (u | 0x80000000u);   // order-isomorphic for all floats
        u64 key = ((u64)u << 32) | (unsigned)p;
        if (key < bd[11]) {
#pragma unroll
            for (int j = 11; j > 0; --j) {
                bool keep = (key >= bd[j]);
                u64 sh = (key >= bd[j - 1]) ? key : bd[j - 1];
                bd[j] = keep ? bd[j] : sh;
            }
            if (key < bd[0]) bd[0] = key;
        }
    }

    // per-wave: 12 rounds of wave min-pop -> sd[w][r]
#pragma unroll
    for (int r = 0; r < KNN_K; ++r) {
        u64 cv = bd[0];
#pragma unroll
        for (int off = 1; off < 64; off <<= 1) {
            u64 ov = __shfl_xor(cv, off);
            cv = (ov < cv) ? ov : cv;
        }
        if (lane == 0) sd[w][r] = cv;
        if (cv == bd[0]) {  // winner lane pops its (sorted) head; keys unique
#pragma unroll
            for (int j = 0; j < 11; ++j) bd[j] = bd[j + 1];
            bd[11] = ~0ULL;
        }
    }
    __syncthreads();

    // even waves merge their query's 24 candidates
    if (sw == 0) {
        u64 cd = (lane < 24) ? sd[2 * qi + (lane >= 12 ? 1 : 0)][lane >= 12 ? lane - 12 : lane]
                             : ~0ULL;
#pragma unroll
        for (int r = 0; r < KNN_K; ++r) {
            u64 mv = cd;
#pragma unroll
            for (int off = 1; off < 64; off <<= 1) {
                u64 ov = __shfl_xor(mv, off);
                mv = (ov < mv) ? ov : mv;
            }
            if (lane == 0) kidx[qi][r] = (int)(unsigned)(mv & 0xFFFFFFFFull);
            if (cd == mv) cd = ~0ULL;
        }
    }
    __syncthreads();
}

// GEMM phase: block = 4 queries (64 rows, 12 valid/query) x 1024 cols; 8 waves of 64x128.
// Per K-step stage 64x32 f32 -> bf16 LDS (double-buffered, [64][40] pad); B direct bf16.
template <int KD>
__device__ __forceinline__ void gemm_body(int mblk, const float* __restrict__ feat,
                                          const int (*kidx)[KNN_K],
                                          const ushort_t* __restrict__ Wb,
                                          const float* __restrict__ bias,
                                          const float* __restrict__ gamma,
                                          const float* __restrict__ beta,
                                          const float* __restrict__ mean,
                                          const float* __restrict__ var,
                                          float* __restrict__ out,
                                          ushort_t (*abuf)[64][40]) {
    const int NK = KD / 32;
    int tid = threadIdx.x;
    int w = tid >> 6, lane = tid & 63;
    int lrow = lane & 15, kgrp = lane >> 4;

    // staging role: 8 threads per row, 4 floats each
    int r = tid >> 3, seg = tid & 7;
    int q = mblk * 4 + (r >> 4);
    int k = r & 15;
    bool valid = (k < KNN_K);
    int b = q >> 5;
    int src = valid ? kidx[r >> 4][k] : 0;
    const float* srcp = feat + ((size_t)b * NPTS + src) * KD + seg * 4;

    f32x4 acc[4][8];
#pragma unroll
    for (int mi = 0; mi < 4; ++mi)
#pragma unroll
        for (int ni = 0; ni < 8; ++ni) {
            f32x4 z = {0.f, 0.f, 0.f, 0.f};
            acc[mi][ni] = z;
        }

    // prologue: stage slab 0
    {
        float4 v = {0.f, 0.f, 0.f, 0.f};
        if (valid) v = *reinterpret_cast<const float4*>(srcp);
        ushort4 u;
        u.x = f2bf(v.x); u.y = f2bf(v.y); u.z = f2bf(v.z); u.w = f2bf(v.w);
        *reinterpret_cast<ushort4*>(&abuf[0][r][seg * 4]) = u;
    }
    __syncthreads();

    for (int kk = 0; kk < NK; ++kk) {
        int cur = kk & 1;
        float4 nv = {0.f, 0.f, 0.f, 0.f};
        if (kk + 1 < NK && valid)
            nv = *reinterpret_cast<const float4*>(srcp + (kk + 1) * 32);

        bf16x8 a[4];
#pragma unroll
        for (int mf = 0; mf < 4; ++mf)
            a[mf] = *reinterpret_cast<const bf16x8*>(&abuf[cur][mf * 16 + lrow][kgrp * 8]);

#pragma unroll
        for (int nf = 0; nf < 8; ++nf) {
            int col = w * 128 + nf * 16 + lrow;
            const ushort_t* bp = Wb + (size_t)col * KD + kk * 32 + kgrp * 8;
            bf16x8 bfr = *reinterpret_cast<const bf16x8*>(bp);
#pragma unroll
            for (int mf = 0; mf < 4; ++mf)
                acc[mf][nf] = __builtin_amdgcn_mfma_f32_16x16x32_bf16(a[mf], bfr, acc[mf][nf], 0, 0, 0);
        }

        if (kk + 1 < NK) {
            ushort4 u;
            u.x = f2bf(nv.x); u.y = f2bf(nv.y); u.z = f2bf(nv.z); u.w = f2bf(nv.w);
            *reinterpret_cast<ushort4*>(&abuf[cur ^ 1][r][seg * 4]) = u;
        }
        __syncthreads();
    }

    // epilogue: BN + ReLU + max over rows 0..11; frag rows = kgrp*4+e
#pragma unroll
    for (int nf = 0; nf < 8; ++nf) {
        int col = w * 128 + nf * 16 + lrow;
        float sc = gamma[col] / sqrtf(var[col] + 1e-5f);
        float sh = (bias[col] - mean[col]) * sc + beta[col];
#pragma unroll
        for (int mf = 0; mf < 4; ++mf) {
            float m;
            if (kgrp < 3) {
                float y0 = fmaxf(acc[mf][nf][0] * sc + sh, 0.0f);
                float y1 = fmaxf(acc[mf][nf][1] * sc + sh, 0.0f);
                float y2 = fmaxf(acc[mf][nf][2] * sc + sh, 0.0f);
                float y3 = fmaxf(acc[mf][nf][3] * sc + sh, 0.0f);
                m = fmaxf(fmaxf(y0, y1), fmaxf(y2, y3));
            } else {
                m = -1e30f;  // pad rows 12..15
            }
            m = fmaxf(m, __shfl_xor(m, 16));
            m = fmaxf(m, __shfl_xor(m, 32));
            if (kgrp == 0) out[(size_t)(mblk * 4 + mf) * DOUT + col] = m;
        }
    }
}

struct GP {
    const float* feature_s; const float* xyz_s;
    const float* feature_t; const float* xyz_t;
    const float* new_xyz;
    const ushort_t* Wb_s; const ushort_t* Wb_t;
    const float* bias_s; const float* gamma_s; const float* beta_s;
    const float* mean_s; const float* var_s;
    const float* bias_t; const float* gamma_t; const float* beta_t;
    const float* mean_t; const float* var_t;
    float* out;
};

__global__ __launch_bounds__(512, 2) void knn_gemm_kernel(GP P) {
    __shared__ ushort_t abuf[2][64][40];
    __shared__ u64 sd[8][KNN_K];
    __shared__ int kidx[4][KNN_K];

    int bid = blockIdx.x;
    bool is_t = (bid < 128);
    int mblk = is_t ? bid : bid - 128;
    int q0 = mblk * 4;
    int b = q0 >> 5;

    const float* pts = (is_t ? P.xyz_t : P.xyz_s) + (size_t)b * NPTS * 3;
    knn_phase(pts, P.new_xyz, q0, sd, kidx);

    if (is_t) {
        gemm_body<DT>(mblk, P.feature_t, kidx, P.Wb_t, P.bias_t, P.gamma_t, P.beta_t,
                      P.mean_t, P.var_t, P.out + (size_t)512 * 1024, abuf);
    } else {
        gemm_body<DS>(mblk, P.feature_s, kidx, P.Wb_s, P.bias_s, P.gamma_s, P.beta_s,
                      P.mean_s, P.var_s, P.out, abuf);
    }
}

extern "C" void kernel_launch(void* const* d_in, const int* in_sizes, int n_in,
                              void* d_out, int out_size, void* d_ws, size_t ws_size,
                              hipStream_t stream) {
    const float* feature_s = (const float*)d_in[0];
    const float* xyz_s     = (const float*)d_in[1];
    const float* feature_t = (const float*)d_in[2];
    const float* xyz_t     = (const float*)d_in[3];
    const float* Ws        = (const float*)d_in[4];
    const float* Wt        = (const float*)d_in[10];
    float* out = (float*)d_out;

    char* ws = (char*)d_ws;
    float* new_xyz  = (float*)(ws + 0);
    ushort_t* Wb_s  = (ushort_t*)(ws + 57344);
    ushort_t* Wb_t  = (ushort_t*)(ws + 581632);

    fps_convw_kernel<<<256, 512, 0, stream>>>(xyz_t, new_xyz, Wt, Wb_t, Ws, Wb_s);

    GP P;
    P.feature_s = feature_s; P.xyz_s = xyz_s;
    P.feature_t = feature_t; P.xyz_t = xyz_t;
    P.new_xyz = new_xyz;
    P.Wb_s = Wb_s; P.Wb_t = Wb_t;
    P.bias_s = (const float*)d_in[5];  P.gamma_s = (const float*)d_in[6];
    P.beta_s = (const float*)d_in[7];  P.mean_s  = (const float*)d_in[8];
    P.var_s  = (const float*)d_in[9];
    P.bias_t = (const float*)d_in[11]; P.gamma_t = (const float*)d_in[12];
    P.beta_t = (const float*)d_in[13]; P.mean_t  = (const float*)d_in[14];
    P.var_t  = (const float*)d_in[15];
    P.out = out;

    knn_gemm_kernel<<<256, 512, 0, stream>>>(P);
}